// Round 4
// baseline (141.445 us; speedup 1.0000x reference)
//
#include <hip/hip_runtime.h>
#include <math.h>
#include <stdint.h>

#define NB 4
#define LQ 768
#define NH 8
#define NE 64
#define ND 192   // 3*E augmented feature dim
#define TEMP 0.125f

typedef _Float16 f16;
typedef __attribute__((ext_vector_type(8))) _Float16 f16x8;
typedef __attribute__((ext_vector_type(4))) float f32x4;

// Async global->LDS 16B: HW writes lds_base + lane*16. lds_base must be
// wave-uniform; global address is per-lane.
__device__ __forceinline__ void stage16(f16* lds_base, const f16* g, int lane) {
#if __has_builtin(__builtin_amdgcn_global_load_lds)
    __builtin_amdgcn_global_load_lds(
        (const __attribute__((address_space(1))) uint32_t*)g,
        (__attribute__((address_space(3))) uint32_t*)lds_base, 16, 0, 0);
#else
    *(uint4*)((char*)lds_base + lane * 16) = *(const uint4*)g;
#endif
}

// Pure-VALU 16-lane reductions via DPP (no DS-pipe traffic). Verified round-2.
// xor1 = quad_perm[1,0,3,2]=0xB1, xor2 = quad_perm[2,3,0,1]=0x4E,
// 8-swap = row_half_mirror (0x141), 16-swap = row_mirror (0x140).
template <int CTRL>
__device__ __forceinline__ float dppf(float x) {
    union { float f; int i; } u, r;
    u.f = x;
    r.i = __builtin_amdgcn_update_dpp(u.i, u.i, CTRL, 0xF, 0xF, false);
    return r.f;
}
__device__ __forceinline__ float red16_max(float x) {
    x = fmaxf(x, dppf<0xB1>(x));
    x = fmaxf(x, dppf<0x4E>(x));
    x = fmaxf(x, dppf<0x141>(x));
    x = fmaxf(x, dppf<0x140>(x));
    return x;
}
__device__ __forceinline__ float red16_sum(float x) {
    x += dppf<0xB1>(x);
    x += dppf<0x4E>(x);
    x += dppf<0x141>(x);
    x += dppf<0x140>(x);
    return x;
}

// ---------------- prep: augmented f16 Q' and K', 8 elems/thread ----------------
__global__ __launch_bounds__(256) void sinattn_prep(
    const float* __restrict__ Q, const float* __restrict__ K,
    const float* __restrict__ freqs, const float* __restrict__ offsets,
    const float* __restrict__ gains, const float* __restrict__ gate,
    f16* __restrict__ Qf, f16* __restrict__ Kf)
{
    int idx = blockIdx.x * 256 + threadIdx.x;   // ((n*L+l)*8 + h)*8 + eg
    int eg = idx & 7, e0 = eg << 3;
    int h  = (idx >> 3) & 7;
    int t  = idx >> 6;                          // n*L + l
    int l  = t % LQ;
    int n  = t / LQ;
    int nh = (n << 3) | h;
    int he = (h << 6) | e0;

    const float* qp = Q + (size_t)idx * 8;      // == ((t*8+h)*64 + e0)
    const float* kp = K + (size_t)idx * 8;
    float4 q0 = *(const float4*)qp, q1 = *(const float4*)(qp + 4);
    float4 k0 = *(const float4*)kp, k1 = *(const float4*)(kp + 4);
    float qv[8] = {q0.x,q0.y,q0.z,q0.w, q1.x,q1.y,q1.z,q1.w};
    float kv[8] = {k0.x,k0.y,k0.z,k0.w, k1.x,k1.y,k1.z,k1.w};

    float4 fA = *(const float4*)(freqs   + he), fB = *(const float4*)(freqs   + he + 4);
    float4 oA = *(const float4*)(offsets + he), oB = *(const float4*)(offsets + he + 4);
    float4 gA = *(const float4*)(gains   + he), gB = *(const float4*)(gains   + he + 4);
    float4 tA = *(const float4*)(gate    + he), tB = *(const float4*)(gate    + he + 4);
    float fv[8] = {fA.x,fA.y,fA.z,fA.w, fB.x,fB.y,fB.z,fB.w};
    float ov[8] = {oA.x,oA.y,oA.z,oA.w, oB.x,oB.y,oB.z,oB.w};
    float gv[8] = {gA.x,gA.y,gA.z,gA.w, gB.x,gB.y,gB.z,gB.w};
    float tv[8] = {tA.x,tA.y,tA.z,tA.w, tB.x,tB.y,tB.z,tB.w};

    f16x8 oq0, oq1, oq2, ok0, ok1, ok2;
    float lf = (float)l;
    #pragma unroll
    for (int j = 0; j < 8; ++j) {
        float f  = 0.5f / (1.0f + __expf(-fv[j]));        // sigmoid/2 (revolutions)
        float gn = gv[j];
        float sp = (gn > 15.0f) ? gn : __logf(1.0f + __expf(gn));
        float gt = tv[j];
        float a  = (1.0f - gt) * sp * sp;
        // exact frac(l*f): split f at 12 mantissa bits
        float fh = __uint_as_float(__float_as_uint(f) & 0xFFFFF000u);
        float fl = f - fh;
        float t0 = lf * fh;
        float tr = t0 - floorf(t0);
        tr = __builtin_fmaf(lf, fl, tr);
        float pk = 6.28318530717958647f * tr;
        float pq = pk + ov[j];
        float sq = __sinf(pq), cq = __cosf(pq);
        float sk = __sinf(pk), ck = __cosf(pk);
        oq0[j] = (f16)(qv[j] * a * cq);
        oq1[j] = (f16)(qv[j] * a * sq);
        oq2[j] = (f16)(qv[j] * gt);
        ok0[j] = (f16)(kv[j] * ck);
        ok1[j] = (f16)(kv[j] * sk);
        ok2[j] = (f16)(kv[j]);
    }
    size_t base = ((size_t)nh * LQ + l) * ND + e0;
    *(f16x8*)(Qf + base)            = oq0;
    *(f16x8*)(Qf + base + NE)       = oq1;
    *(f16x8*)(Qf + base + 2 * NE)   = oq2;
    *(f16x8*)(Kf + base)            = ok0;
    *(f16x8*)(Kf + base + NE)       = ok1;
    *(f16x8*)(Kf + base + 2 * NE)   = ok2;
}

// ---------------- V transpose: [n][s][h][e] fp32 -> Vt[nh][e][s] f16 ----------------
__global__ __launch_bounds__(256) void sinattn_vt(
    const float* __restrict__ V, f16* __restrict__ Vt)
{
    __shared__ f16 tile[64][72];
    int b = blockIdx.x;
    int st = b % 12, nh = b / 12;
    int n = nh >> 3, h = nh & 7;
    int s0 = st * 64;
    int tid = threadIdx.x;

    int sl = tid >> 2, e0 = (tid & 3) << 4;
    const float4* vp = (const float4*)(V + ((size_t)(n * LQ + s0 + sl) * NH + h) * NE + e0);
    float4 a0 = vp[0], a1 = vp[1], a2 = vp[2], a3 = vp[3];
    float vv[16] = { a0.x,a0.y,a0.z,a0.w, a1.x,a1.y,a1.z,a1.w,
                     a2.x,a2.y,a2.z,a2.w, a3.x,a3.y,a3.z,a3.w };
    #pragma unroll
    for (int j = 0; j < 16; ++j) tile[e0 + j][sl] = (f16)vv[j];
    __syncthreads();

    int er = tid >> 2, sc = tid & 3;
    f16* op = Vt + ((size_t)nh * NE + er) * LQ + s0 + sc * 16;
    *(uint4*)op       = *(const uint4*)&tile[er][sc * 16];
    *(uint4*)(op + 8) = *(const uint4*)&tile[er][sc * 16 + 8];
}

// ---------------- flash attention, f16 MFMA, async dbuf staging ----------------
// grid 256 (= CU count, perfectly balanced): nh = bid&31, lt = bid>>5
// (8 tiles of 96 q-rows). block 128 (2 waves, 48 q-rows/wave = three 16-row
// A-tiles). Each K/V B-fragment ds_read feeds 3 MFMAs. Softmax reductions are
// DPP (pure VALU). Layouts identical to the round-0/2 verified kernel.
// LDS: K chunks stored as 16B chunks, phys chunk p = r*24 + ((c&~7)|((c&7)^(r&7)))
//      V chunks: p = r*8 + (c ^ (r&7)). XOR swizzle -> uniform bank spread on
//      both the lane-linear async writes and the B-fragment b128 reads.
__global__ __launch_bounds__(128, 2) void sinattn_flash(
    const f16* __restrict__ Qf, const f16* __restrict__ Kf, const f16* __restrict__ Vt,
    const float* __restrict__ mask, const float* __restrict__ keylen,
    float* __restrict__ out)
{
    __shared__ __attribute__((aligned(16))) f16 sK[2][64 * 24 * 8];  // 24 KB each
    __shared__ __attribute__((aligned(16))) f16 sV[2][64 * 8 * 8];   // 8 KB each
    __shared__ __attribute__((aligned(16))) f16 sP[2][48 * 72];      // per-wave

    int tid  = threadIdx.x;
    int wv   = tid >> 6;
    int lane = tid & 63;
    int grp  = lane >> 4;
    int r16  = lane & 15;
    int swz  = r16 & 7;

    int bid = blockIdx.x;
    int nh  = bid & 31;
    int lt  = bid >> 5;
    int n   = nh >> 3;
    int l0  = lt * 96;
    int qrow0 = l0 + wv * 48;            // this wave's first q-row

    // per-lane swizzled global offsets for staging (128 threads/block)
    int goffK[12], goffV[4];
    #pragma unroll
    for (int i = 0; i < 12; ++i) {
        int p = i * 128 + tid;
        int r = p / 24, c = p - r * 24;
        int cl = (c & ~7) | ((c & 7) ^ (r & 7));
        goffK[i] = r * ND + cl * 8;
    }
    #pragma unroll
    for (int i = 0; i < 4; ++i) {
        int p = i * 128 + tid;
        int r = p >> 3, c = p & 7;
        goffV[i] = r * LQ + (c ^ (r & 7)) * 8;
    }
    const f16* Kb = Kf + (size_t)nh * LQ * ND;
    const f16* Vb = Vt + (size_t)nh * NE * LQ;

    // issue chunk 0 into buffer 0 (latency overlaps qf loads below)
    {
        #pragma unroll
        for (int i = 0; i < 12; ++i)
            stage16(&sK[0][(i * 128 + wv * 64) * 8], Kb + goffK[i], lane);
        #pragma unroll
        for (int i = 0; i < 4; ++i)
            stage16(&sV[0][(i * 128 + wv * 64) * 8], Vb + goffV[i], lane);
    }

    // Q fragments (A-layout) from global, live whole kernel: 72 VGPRs
    f16x8 qf[3][6];
    #pragma unroll
    for (int ti = 0; ti < 3; ++ti) {
        size_t rbase = ((size_t)nh * LQ + qrow0 + ti * 16 + r16) * ND + grp * 8;
        #pragma unroll
        for (int d0 = 0; d0 < 6; ++d0)
            qf[ti][d0] = *(const f16x8*)(Qf + rbase + d0 * 32);
    }

    float m_i[3][4], l_i[3][4];
    f32x4 O[3][4];
    #pragma unroll
    for (int ti = 0; ti < 3; ++ti)
        #pragma unroll
        for (int rr = 0; rr < 4; ++rr) { m_i[ti][rr] = -INFINITY; l_i[ti][rr] = 0.f; }
    #pragma unroll
    for (int ti = 0; ti < 3; ++ti)
        #pragma unroll
        for (int tt = 0; tt < 4; ++tt)
            #pragma unroll
            for (int rr = 0; rr < 4; ++rr) O[ti][tt][rr] = 0.f;

    for (int c = 0; c < 12; ++c) {
        int cur = c & 1;
        int s0  = c * 64;
        __syncthreads();   // drains vmcnt: sK/sV[cur] landed; prev compute done

        if (c < 11) {      // prefetch next chunk; in flight during this compute
            const f16* kg = Kb + (s0 + 64) * ND;
            const f16* vg = Vb + (s0 + 64);
            #pragma unroll
            for (int i = 0; i < 12; ++i)
                stage16(&sK[cur ^ 1][(i * 128 + wv * 64) * 8], kg + goffK[i], lane);
            #pragma unroll
            for (int i = 0; i < 4; ++i)
                stage16(&sV[cur ^ 1][(i * 128 + wv * 64) * 8], vg + goffV[i], lane);
        }

        // mask / keylen (zero-valued but semantically required; L2-resident)
        float klv[4], mreg[3][4][4];
        #pragma unroll
        for (int j = 0; j < 4; ++j) klv[j] = keylen[n * LQ + s0 + j * 16 + r16];
        #pragma unroll
        for (int ti = 0; ti < 3; ++ti)
            #pragma unroll
            for (int rr = 0; rr < 4; ++rr) {
                int lrow = qrow0 + ti * 16 + grp * 4 + rr;
                #pragma unroll
                for (int j = 0; j < 4; ++j)
                    mreg[ti][rr][j] = mask[lrow * LQ + s0 + j * 16 + r16];
            }

        // S = Q'.K'^T  (f16 MFMA; each B-frag feeds all three row tiles)
        f32x4 st[3][4];
        #pragma unroll
        for (int ti = 0; ti < 3; ++ti)
            #pragma unroll
            for (int j = 0; j < 4; ++j)
                #pragma unroll
                for (int rr = 0; rr < 4; ++rr) st[ti][j][rr] = 0.f;
        #pragma unroll
        for (int d0 = 0; d0 < 6; ++d0) {
            #pragma unroll
            for (int j = 0; j < 4; ++j) {
                int cc = d0 * 4 + grp;
                int cl = (cc & ~7) | ((cc & 7) ^ swz);
                f16x8 bf = *(const f16x8*)&sK[cur][((j * 16 + r16) * 24 + cl) * 8];
                st[0][j] = __builtin_amdgcn_mfma_f32_16x16x32_f16(qf[0][d0], bf, st[0][j], 0, 0, 0);
                st[1][j] = __builtin_amdgcn_mfma_f32_16x16x32_f16(qf[1][d0], bf, st[1][j], 0, 0, 0);
                st[2][j] = __builtin_amdgcn_mfma_f32_16x16x32_f16(qf[2][d0], bf, st[2][j], 0, 0, 0);
            }
        }

        // online softmax (C layout: col=r16+16j, row=grp*4+rr), DPP reductions
        #pragma unroll
        for (int ti = 0; ti < 3; ++ti) {
            #pragma unroll
            for (int rr = 0; rr < 4; ++rr) {
                float lg[4];
                float mx = -INFINITY;
                #pragma unroll
                for (int j = 0; j < 4; ++j) {
                    lg[j] = TEMP * (st[ti][j][rr] + mreg[ti][rr][j] + klv[j]);
                    mx = fmaxf(mx, lg[j]);
                }
                mx = red16_max(mx);
                float mnew  = fmaxf(m_i[ti][rr], mx);
                float alpha = __expf(m_i[ti][rr] - mnew);
                float rs = 0.f;
                #pragma unroll
                for (int j = 0; j < 4; ++j) {
                    float p = __expf(lg[j] - mnew);
                    rs += p;
                    sP[wv][(ti * 16 + grp * 4 + rr) * 72 + j * 16 + r16] = (f16)p;
                }
                rs = red16_sum(rs);
                l_i[ti][rr] = l_i[ti][rr] * alpha + rs;
                m_i[ti][rr] = mnew;
                #pragma unroll
                for (int tt = 0; tt < 4; ++tt) O[ti][tt][rr] *= alpha;
            }
        }
        // no barrier: sP round-trip is per-wave; LDS ops in-order per wave

        // O += P.V  (each V-frag feeds all three row tiles)
        #pragma unroll
        for (int kk = 0; kk < 2; ++kk) {
            f16x8 pa0 = *(const f16x8*)&sP[wv][(r16) * 72 + kk * 32 + grp * 8];
            f16x8 pa1 = *(const f16x8*)&sP[wv][(16 + r16) * 72 + kk * 32 + grp * 8];
            f16x8 pa2 = *(const f16x8*)&sP[wv][(32 + r16) * 72 + kk * 32 + grp * 8];
            #pragma unroll
            for (int tt = 0; tt < 4; ++tt) {
                int cc = kk * 4 + grp;
                f16x8 vb = *(const f16x8*)&sV[cur][((tt * 16 + r16) * 8 + (cc ^ swz)) * 8];
                O[0][tt] = __builtin_amdgcn_mfma_f32_16x16x32_f16(pa0, vb, O[0][tt], 0, 0, 0);
                O[1][tt] = __builtin_amdgcn_mfma_f32_16x16x32_f16(pa1, vb, O[1][tt], 0, 0, 0);
                O[2][tt] = __builtin_amdgcn_mfma_f32_16x16x32_f16(pa2, vb, O[2][tt], 0, 0, 0);
            }
        }
    }

    // epilogue: normalize, write out[n][l][h][e] (fp32)
    #pragma unroll
    for (int ti = 0; ti < 3; ++ti) {
        #pragma unroll
        for (int rr = 0; rr < 4; ++rr) {
            float inv = 1.0f / l_i[ti][rr];
            int lrow = qrow0 + ti * 16 + grp * 4 + rr;
            float* op = out + ((size_t)(n * LQ + lrow) * NH + (nh & 7)) * NE;
            #pragma unroll
            for (int tt = 0; tt < 4; ++tt)
                op[tt * 16 + r16] = O[ti][tt][rr] * inv;
        }
    }
}

extern "C" void kernel_launch(void* const* d_in, const int* in_sizes, int n_in,
                              void* d_out, int out_size, void* d_ws, size_t ws_size,
                              hipStream_t stream)
{
    const float* Q      = (const float*)d_in[0];
    const float* K      = (const float*)d_in[1];
    const float* V      = (const float*)d_in[2];
    const float* mask   = (const float*)d_in[3];
    const float* keylen = (const float*)d_in[4];
    const float* freqs  = (const float*)d_in[5];
    const float* offs   = (const float*)d_in[6];
    const float* gains  = (const float*)d_in[7];
    const float* gate   = (const float*)d_in[8];
    float* out = (float*)d_out;

    const size_t P = (size_t)NB * NH * LQ * ND;   // 4.72M elems / plane
    f16* Qf = (f16*)d_ws;
    f16* Kf = Qf + P;
    f16* Vt = Kf + P;                             // 32*64*768 f16 = 3.1 MB

    sinattn_prep<<<768, 256, 0, stream>>>(Q, K, freqs, offs, gains, gate, Qf, Kf);
    sinattn_vt<<<384, 256, 0, stream>>>(V, Vt);
    sinattn_flash<<<NB * NH * (LQ / 96), 128, 0, stream>>>(Qf, Kf, Vt,
                                                           mask, keylen, out);
}

// Round 5
// 116.916 us; speedup vs baseline: 1.2098x; 1.2098x over previous
//
#include <hip/hip_runtime.h>
#include <math.h>
#include <stdint.h>

#define NB 4
#define LQ 768
#define NH 8
#define NE 64
#define ND 192   // 3*E augmented feature dim
// TEMP * log2(e): softmax computed in exp2 domain (1 transcendental per p)
#define TEMP2 0.18033688011112042f

typedef _Float16 f16;
typedef __attribute__((ext_vector_type(8))) _Float16 f16x8;
typedef __attribute__((ext_vector_type(4))) float f32x4;

// Async global->LDS 16B: HW writes lds_base + lane*16. lds_base must be
// wave-uniform; global address is per-lane.
__device__ __forceinline__ void stage16(f16* lds_base, const f16* g, int lane) {
#if __has_builtin(__builtin_amdgcn_global_load_lds)
    __builtin_amdgcn_global_load_lds(
        (const __attribute__((address_space(1))) uint32_t*)g,
        (__attribute__((address_space(3))) uint32_t*)lds_base, 16, 0, 0);
#else
    *(uint4*)((char*)lds_base + lane * 16) = *(const uint4*)g;
#endif
}

__device__ __forceinline__ float fexp2(float x) {
#if __has_builtin(__builtin_amdgcn_exp2f)
    return __builtin_amdgcn_exp2f(x);
#else
    return exp2f(x);
#endif
}

// Pure-VALU 16-lane reductions via DPP (no DS-pipe traffic). Verified round-2.
// xor1 = quad_perm[1,0,3,2]=0xB1, xor2 = quad_perm[2,3,0,1]=0x4E,
// 8-swap = row_half_mirror (0x141), 16-swap = row_mirror (0x140).
template <int CTRL>
__device__ __forceinline__ float dppf(float x) {
    union { float f; int i; } u, r;
    u.f = x;
    r.i = __builtin_amdgcn_update_dpp(u.i, u.i, CTRL, 0xF, 0xF, false);
    return r.f;
}
__device__ __forceinline__ float red16_max(float x) {
    x = fmaxf(x, dppf<0xB1>(x));
    x = fmaxf(x, dppf<0x4E>(x));
    x = fmaxf(x, dppf<0x141>(x));
    x = fmaxf(x, dppf<0x140>(x));
    return x;
}
__device__ __forceinline__ float red16_sum(float x) {
    x += dppf<0xB1>(x);
    x += dppf<0x4E>(x);
    x += dppf<0x141>(x);
    x += dppf<0x140>(x);
    return x;
}

// ---------------- prep: augmented f16 Q' and K', 8 elems/thread ----------------
__global__ __launch_bounds__(256) void sinattn_prep(
    const float* __restrict__ Q, const float* __restrict__ K,
    const float* __restrict__ freqs, const float* __restrict__ offsets,
    const float* __restrict__ gains, const float* __restrict__ gate,
    f16* __restrict__ Qf, f16* __restrict__ Kf)
{
    int idx = blockIdx.x * 256 + threadIdx.x;   // ((n*L+l)*8 + h)*8 + eg
    int eg = idx & 7, e0 = eg << 3;
    int h  = (idx >> 3) & 7;
    int t  = idx >> 6;                          // n*L + l
    int l  = t % LQ;
    int n  = t / LQ;
    int nh = (n << 3) | h;
    int he = (h << 6) | e0;

    const float* qp = Q + (size_t)idx * 8;      // == ((t*8+h)*64 + e0)
    const float* kp = K + (size_t)idx * 8;
    float4 q0 = *(const float4*)qp, q1 = *(const float4*)(qp + 4);
    float4 k0 = *(const float4*)kp, k1 = *(const float4*)(kp + 4);
    float qv[8] = {q0.x,q0.y,q0.z,q0.w, q1.x,q1.y,q1.z,q1.w};
    float kv[8] = {k0.x,k0.y,k0.z,k0.w, k1.x,k1.y,k1.z,k1.w};

    float4 fA = *(const float4*)(freqs   + he), fB = *(const float4*)(freqs   + he + 4);
    float4 oA = *(const float4*)(offsets + he), oB = *(const float4*)(offsets + he + 4);
    float4 gA = *(const float4*)(gains   + he), gB = *(const float4*)(gains   + he + 4);
    float4 tA = *(const float4*)(gate    + he), tB = *(const float4*)(gate    + he + 4);
    float fv[8] = {fA.x,fA.y,fA.z,fA.w, fB.x,fB.y,fB.z,fB.w};
    float ov[8] = {oA.x,oA.y,oA.z,oA.w, oB.x,oB.y,oB.z,oB.w};
    float gv[8] = {gA.x,gA.y,gA.z,gA.w, gB.x,gB.y,gB.z,gB.w};
    float tv[8] = {tA.x,tA.y,tA.z,tA.w, tB.x,tB.y,tB.z,tB.w};

    f16x8 oq0, oq1, oq2, ok0, ok1, ok2;
    float lf = (float)l;
    #pragma unroll
    for (int j = 0; j < 8; ++j) {
        float f  = 0.5f / (1.0f + __expf(-fv[j]));        // sigmoid/2 (revolutions)
        float gn = gv[j];
        float sp = (gn > 15.0f) ? gn : __logf(1.0f + __expf(gn));
        float gt = tv[j];
        float a  = (1.0f - gt) * sp * sp;
        // exact frac(l*f): split f at 12 mantissa bits
        float fh = __uint_as_float(__float_as_uint(f) & 0xFFFFF000u);
        float fl = f - fh;
        float t0 = lf * fh;
        float tr = t0 - floorf(t0);
        tr = __builtin_fmaf(lf, fl, tr);
        float pk = 6.28318530717958647f * tr;
        float pq = pk + ov[j];
        float sq = __sinf(pq), cq = __cosf(pq);
        float sk = __sinf(pk), ck = __cosf(pk);
        oq0[j] = (f16)(qv[j] * a * cq);
        oq1[j] = (f16)(qv[j] * a * sq);
        oq2[j] = (f16)(qv[j] * gt);
        ok0[j] = (f16)(kv[j] * ck);
        ok1[j] = (f16)(kv[j] * sk);
        ok2[j] = (f16)(kv[j]);
    }
    size_t base = ((size_t)nh * LQ + l) * ND + e0;
    *(f16x8*)(Qf + base)            = oq0;
    *(f16x8*)(Qf + base + NE)       = oq1;
    *(f16x8*)(Qf + base + 2 * NE)   = oq2;
    *(f16x8*)(Kf + base)            = ok0;
    *(f16x8*)(Kf + base + NE)       = ok1;
    *(f16x8*)(Kf + base + 2 * NE)   = ok2;
}

// ---------------- V transpose: [n][s][h][e] fp32 -> Vt[nh][e][s] f16 ----------------
__global__ __launch_bounds__(256) void sinattn_vt(
    const float* __restrict__ V, f16* __restrict__ Vt)
{
    __shared__ f16 tile[64][72];
    int b = blockIdx.x;
    int st = b % 12, nh = b / 12;
    int n = nh >> 3, h = nh & 7;
    int s0 = st * 64;
    int tid = threadIdx.x;

    int sl = tid >> 2, e0 = (tid & 3) << 4;
    const float4* vp = (const float4*)(V + ((size_t)(n * LQ + s0 + sl) * NH + h) * NE + e0);
    float4 a0 = vp[0], a1 = vp[1], a2 = vp[2], a3 = vp[3];
    float vv[16] = { a0.x,a0.y,a0.z,a0.w, a1.x,a1.y,a1.z,a1.w,
                     a2.x,a2.y,a2.z,a2.w, a3.x,a3.y,a3.z,a3.w };
    #pragma unroll
    for (int j = 0; j < 16; ++j) tile[e0 + j][sl] = (f16)vv[j];
    __syncthreads();

    int er = tid >> 2, sc = tid & 3;
    f16* op = Vt + ((size_t)nh * NE + er) * LQ + s0 + sc * 16;
    *(uint4*)op       = *(const uint4*)&tile[er][sc * 16];
    *(uint4*)(op + 8) = *(const uint4*)&tile[er][sc * 16 + 8];
}

// ---------------- flash attention, f16 MFMA, async dbuf staging ----------------
// grid 512 (= 2 blocks/CU, perfectly balanced): nh = bid&31, lt = bid>>5
// (16 tiles of 48 q-rows). block 192 (3 waves, one 16-row A-tile each).
// 6 waves/CU everywhere: wave-level overlap of DS / VALU / MFMA phases.
// Per-wave code identical to the verified round-0/2 single-tile path.
// LDS: K chunks stored as 16B chunks, phys chunk p = r*24 + ((c&~7)|((c&7)^(r&7)))
//      V chunks: p = r*8 + (c ^ (r&7)). XOR swizzle -> uniform bank spread on
//      both the lane-linear async writes and the B-fragment b128 reads.
__global__ __launch_bounds__(192) void sinattn_flash(
    const f16* __restrict__ Qf, const f16* __restrict__ Kf, const f16* __restrict__ Vt,
    const float* __restrict__ mask, const float* __restrict__ keylen,
    float* __restrict__ out)
{
    __shared__ __attribute__((aligned(16))) f16 sK[2][64 * 24 * 8];  // 24 KB each
    __shared__ __attribute__((aligned(16))) f16 sV[2][64 * 8 * 8];   // 8 KB each
    __shared__ __attribute__((aligned(16))) f16 sP[3][16 * 72];      // per-wave

    int tid  = threadIdx.x;
    int wv   = tid / 64;                 // 0..2
    int lane = tid & 63;
    int grp  = lane >> 4;
    int r16  = lane & 15;
    int swz  = r16 & 7;

    int bid = blockIdx.x;
    int nh  = bid & 31;
    int lt  = bid >> 5;                  // 0..15
    int n   = nh >> 3;
    int l0  = lt * 48;
    int qrow0 = l0 + wv * 16;            // this wave's q-rows

    // per-lane swizzled global offsets for staging (192 threads/block)
    int goffK[8], goffV[3];
    #pragma unroll
    for (int i = 0; i < 8; ++i) {
        int p = i * 192 + tid;           // 0..1535
        int r = p / 24, c = p - r * 24;
        int cl = (c & ~7) | ((c & 7) ^ (r & 7));
        goffK[i] = r * ND + cl * 8;
    }
    #pragma unroll
    for (int i = 0; i < 3; ++i) {
        int p = i * 192 + tid;           // 0..575 (512 valid)
        int r = p >> 3, c = p & 7;
        goffV[i] = r * LQ + (c ^ (r & 7)) * 8;
    }
    const f16* Kb = Kf + (size_t)nh * LQ * ND;
    const f16* Vb = Vt + (size_t)nh * NE * LQ;

    // issue chunk 0 into buffer 0 (latency overlaps qf loads below)
    {
        #pragma unroll
        for (int i = 0; i < 8; ++i)
            stage16(&sK[0][(i * 192 + wv * 64) * 8], Kb + goffK[i], lane);
        #pragma unroll
        for (int i = 0; i < 2; ++i)
            stage16(&sV[0][(i * 192 + wv * 64) * 8], Vb + goffV[i], lane);
        if (tid < 128)   // waves 0,1 only: wave-uniform branch
            stage16(&sV[0][(384 + wv * 64) * 8], Vb + goffV[2], lane);
    }

    // Q fragments (A-layout) from global, live whole kernel: 24 VGPRs
    f16x8 qf[6];
    {
        size_t rbase = ((size_t)nh * LQ + qrow0 + r16) * ND + grp * 8;
        #pragma unroll
        for (int d0 = 0; d0 < 6; ++d0)
            qf[d0] = *(const f16x8*)(Qf + rbase + d0 * 32);
    }

    float m_i[4], l_i[4];
    f32x4 O[4];
    #pragma unroll
    for (int rr = 0; rr < 4; ++rr) { m_i[rr] = -INFINITY; l_i[rr] = 0.f; }
    #pragma unroll
    for (int tt = 0; tt < 4; ++tt)
        #pragma unroll
        for (int rr = 0; rr < 4; ++rr) O[tt][rr] = 0.f;

    for (int c = 0; c < 12; ++c) {
        int cur = c & 1;
        int s0  = c * 64;
        __syncthreads();   // drains vmcnt: sK/sV[cur] landed; prev compute done

        if (c < 11) {      // prefetch next chunk; in flight during this compute
            const f16* kg = Kb + (s0 + 64) * ND;
            const f16* vg = Vb + (s0 + 64);
            #pragma unroll
            for (int i = 0; i < 8; ++i)
                stage16(&sK[cur ^ 1][(i * 192 + wv * 64) * 8], kg + goffK[i], lane);
            #pragma unroll
            for (int i = 0; i < 2; ++i)
                stage16(&sV[cur ^ 1][(i * 192 + wv * 64) * 8], vg + goffV[i], lane);
            if (tid < 128)
                stage16(&sV[cur ^ 1][(384 + wv * 64) * 8], vg + goffV[2], lane);
        }

        // mask / keylen (zero-valued but semantically required; L2-resident)
        float klv[4], mreg[4][4];
        #pragma unroll
        for (int j = 0; j < 4; ++j) klv[j] = keylen[n * LQ + s0 + j * 16 + r16];
        #pragma unroll
        for (int rr = 0; rr < 4; ++rr) {
            int lrow = qrow0 + grp * 4 + rr;
            #pragma unroll
            for (int j = 0; j < 4; ++j)
                mreg[rr][j] = mask[lrow * LQ + s0 + j * 16 + r16];
        }

        // S = Q'.K'^T  (f16 MFMA)
        f32x4 st[4];
        #pragma unroll
        for (int j = 0; j < 4; ++j)
            #pragma unroll
            for (int rr = 0; rr < 4; ++rr) st[j][rr] = 0.f;
        #pragma unroll
        for (int d0 = 0; d0 < 6; ++d0) {
            #pragma unroll
            for (int j = 0; j < 4; ++j) {
                int cc = d0 * 4 + grp;
                int cl = (cc & ~7) | ((cc & 7) ^ swz);
                f16x8 bf = *(const f16x8*)&sK[cur][((j * 16 + r16) * 24 + cl) * 8];
                st[j] = __builtin_amdgcn_mfma_f32_16x16x32_f16(qf[d0], bf, st[j], 0, 0, 0);
            }
        }

        // online softmax in exp2 domain (C layout: col=r16+16j, row=grp*4+rr)
        #pragma unroll
        for (int rr = 0; rr < 4; ++rr) {
            float lg[4];
            float mx = -INFINITY;
            #pragma unroll
            for (int j = 0; j < 4; ++j) {
                lg[j] = TEMP2 * (st[j][rr] + mreg[rr][j] + klv[j]);
                mx = fmaxf(mx, lg[j]);
            }
            mx = red16_max(mx);
            float mnew  = fmaxf(m_i[rr], mx);
            float alpha = fexp2(m_i[rr] - mnew);
            float rs = 0.f;
            #pragma unroll
            for (int j = 0; j < 4; ++j) {
                float p = fexp2(lg[j] - mnew);
                rs += p;
                sP[wv][(grp * 4 + rr) * 72 + j * 16 + r16] = (f16)p;
            }
            rs = red16_sum(rs);
            l_i[rr] = l_i[rr] * alpha + rs;
            m_i[rr] = mnew;
            #pragma unroll
            for (int tt = 0; tt < 4; ++tt) O[tt][rr] *= alpha;
        }
        // no barrier: sP round-trip is per-wave; LDS ops in-order per wave

        // O += P.V
        #pragma unroll
        for (int kk = 0; kk < 2; ++kk) {
            f16x8 pa = *(const f16x8*)&sP[wv][r16 * 72 + kk * 32 + grp * 8];
            #pragma unroll
            for (int tt = 0; tt < 4; ++tt) {
                int cc = kk * 4 + grp;
                f16x8 vb = *(const f16x8*)&sV[cur][((tt * 16 + r16) * 8 + (cc ^ swz)) * 8];
                O[tt] = __builtin_amdgcn_mfma_f32_16x16x32_f16(pa, vb, O[tt], 0, 0, 0);
            }
        }
    }

    // epilogue: normalize, write out[n][l][h][e] (fp32)
    #pragma unroll
    for (int rr = 0; rr < 4; ++rr) {
        float inv = 1.0f / l_i[rr];
        int lrow = qrow0 + grp * 4 + rr;
        float* op = out + ((size_t)(n * LQ + lrow) * NH + (nh & 7)) * NE;
        #pragma unroll
        for (int tt = 0; tt < 4; ++tt)
            op[tt * 16 + r16] = O[tt][rr] * inv;
    }
}

extern "C" void kernel_launch(void* const* d_in, const int* in_sizes, int n_in,
                              void* d_out, int out_size, void* d_ws, size_t ws_size,
                              hipStream_t stream)
{
    const float* Q      = (const float*)d_in[0];
    const float* K      = (const float*)d_in[1];
    const float* V      = (const float*)d_in[2];
    const float* mask   = (const float*)d_in[3];
    const float* keylen = (const float*)d_in[4];
    const float* freqs  = (const float*)d_in[5];
    const float* offs   = (const float*)d_in[6];
    const float* gains  = (const float*)d_in[7];
    const float* gate   = (const float*)d_in[8];
    float* out = (float*)d_out;

    const size_t P = (size_t)NB * NH * LQ * ND;   // 4.72M elems / plane
    f16* Qf = (f16*)d_ws;
    f16* Kf = Qf + P;
    f16* Vt = Kf + P;                             // 32*64*768 f16 = 3.1 MB

    sinattn_prep<<<768, 256, 0, stream>>>(Q, K, freqs, offs, gains, gate, Qf, Kf);
    sinattn_vt<<<384, 256, 0, stream>>>(V, Vt);
    sinattn_flash<<<NB * NH * (LQ / 48), 192, 0, stream>>>(Qf, Kf, Vt,
                                                           mask, keylen, out);
}

// Round 7
// 114.219 us; speedup vs baseline: 1.2384x; 1.0236x over previous
//
#include <hip/hip_runtime.h>
#include <math.h>
#include <stdint.h>

#define NB 4
#define LQ 768
#define NH 8
#define NE 64
#define ND 192   // 3*E augmented feature dim
// TEMP * log2(e): softmax computed in exp2 domain (1 transcendental per p)
#define TEMP2 0.18033688011112042f

typedef _Float16 f16;
typedef __attribute__((ext_vector_type(8))) _Float16 f16x8;
typedef __attribute__((ext_vector_type(4))) float f32x4;

// Async global->LDS 16B: HW writes lds_base + lane*16. lds_base must be
// wave-uniform; global address is per-lane.
__device__ __forceinline__ void stage16(f16* lds_base, const f16* g, int lane) {
#if __has_builtin(__builtin_amdgcn_global_load_lds)
    __builtin_amdgcn_global_load_lds(
        (const __attribute__((address_space(1))) uint32_t*)g,
        (__attribute__((address_space(3))) uint32_t*)lds_base, 16, 0, 0);
#else
    *(uint4*)((char*)lds_base + lane * 16) = *(const uint4*)g;
#endif
}

__device__ __forceinline__ float fexp2(float x) {
#if __has_builtin(__builtin_amdgcn_exp2f)
    return __builtin_amdgcn_exp2f(x);
#else
    return exp2f(x);
#endif
}

// Pure-VALU 16-lane reductions via DPP (no DS-pipe traffic). Verified r2/r5.
// xor1 = quad_perm[1,0,3,2]=0xB1, xor2 = quad_perm[2,3,0,1]=0x4E,
// 8-swap = row_half_mirror (0x141), 16-swap = row_mirror (0x140).
template <int CTRL>
__device__ __forceinline__ float dppf(float x) {
    union { float f; int i; } u, r;
    u.f = x;
    r.i = __builtin_amdgcn_update_dpp(u.i, u.i, CTRL, 0xF, 0xF, false);
    return r.f;
}
__device__ __forceinline__ float red16_max(float x) {
    x = fmaxf(x, dppf<0xB1>(x));
    x = fmaxf(x, dppf<0x4E>(x));
    x = fmaxf(x, dppf<0x141>(x));
    x = fmaxf(x, dppf<0x140>(x));
    return x;
}
__device__ __forceinline__ float red16_sum(float x) {
    x += dppf<0xB1>(x);
    x += dppf<0x4E>(x);
    x += dppf<0x141>(x);
    x += dppf<0x140>(x);
    return x;
}

// ------- merged prep (blocks 0..767) + V transpose (blocks 768..1151) -------
// prep: augmented f16 Q' and K', 8 elems/thread.
// vt:   [n][s][h][e] fp32 -> Vt[nh][e][s] f16 via LDS tile.
__global__ __launch_bounds__(256) void sinattn_prep(
    const float* __restrict__ Q, const float* __restrict__ K,
    const float* __restrict__ V,
    const float* __restrict__ freqs, const float* __restrict__ offsets,
    const float* __restrict__ gains, const float* __restrict__ gate,
    f16* __restrict__ Qf, f16* __restrict__ Kf, f16* __restrict__ Vt)
{
    __shared__ f16 tile[64][72];
    int bid = blockIdx.x;
    int tid = threadIdx.x;

    if (bid >= 768) {
        // ---- V transpose ----
        int b = bid - 768;
        int st = b % 12, nh = b / 12;
        int n = nh >> 3, h = nh & 7;
        int s0 = st * 64;

        int sl = tid >> 2, e0 = (tid & 3) << 4;
        const float4* vp = (const float4*)(V + ((size_t)(n * LQ + s0 + sl) * NH + h) * NE + e0);
        float4 a0 = vp[0], a1 = vp[1], a2 = vp[2], a3 = vp[3];
        float vv[16] = { a0.x,a0.y,a0.z,a0.w, a1.x,a1.y,a1.z,a1.w,
                         a2.x,a2.y,a2.z,a2.w, a3.x,a3.y,a3.z,a3.w };
        #pragma unroll
        for (int j = 0; j < 16; ++j) tile[e0 + j][sl] = (f16)vv[j];
        __syncthreads();

        int er = tid >> 2, sc = tid & 3;
        f16* op = Vt + ((size_t)nh * NE + er) * LQ + s0 + sc * 16;
        *(uint4*)op       = *(const uint4*)&tile[er][sc * 16];
        *(uint4*)(op + 8) = *(const uint4*)&tile[er][sc * 16 + 8];
        return;
    }

    // ---- prep ----
    int idx = bid * 256 + tid;                  // ((n*L+l)*8 + h)*8 + eg
    int eg = idx & 7, e0 = eg << 3;
    int h  = (idx >> 3) & 7;
    int t  = idx >> 6;                          // n*L + l
    int l  = t % LQ;
    int n  = t / LQ;
    int nh = (n << 3) | h;
    int he = (h << 6) | e0;

    const float* qp = Q + (size_t)idx * 8;      // == ((t*8+h)*64 + e0)
    const float* kp = K + (size_t)idx * 8;
    float4 q0 = *(const float4*)qp, q1 = *(const float4*)(qp + 4);
    float4 k0 = *(const float4*)kp, k1 = *(const float4*)(kp + 4);
    float qv[8] = {q0.x,q0.y,q0.z,q0.w, q1.x,q1.y,q1.z,q1.w};
    float kv[8] = {k0.x,k0.y,k0.z,k0.w, k1.x,k1.y,k1.z,k1.w};

    float4 fA = *(const float4*)(freqs   + he), fB = *(const float4*)(freqs   + he + 4);
    float4 oA = *(const float4*)(offsets + he), oB = *(const float4*)(offsets + he + 4);
    float4 gA = *(const float4*)(gains   + he), gB = *(const float4*)(gains   + he + 4);
    float4 tA = *(const float4*)(gate    + he), tB = *(const float4*)(gate    + he + 4);
    float fv[8] = {fA.x,fA.y,fA.z,fA.w, fB.x,fB.y,fB.z,fB.w};
    float ov[8] = {oA.x,oA.y,oA.z,oA.w, oB.x,oB.y,oB.z,oB.w};
    float gv[8] = {gA.x,gA.y,gA.z,gA.w, gB.x,gB.y,gB.z,gB.w};
    float tv[8] = {tA.x,tA.y,tA.z,tA.w, tB.x,tB.y,tB.z,tB.w};

    f16x8 oq0, oq1, oq2, ok0, ok1, ok2;
    float lf = (float)l;
    #pragma unroll
    for (int j = 0; j < 8; ++j) {
        float f  = 0.5f / (1.0f + __expf(-fv[j]));        // sigmoid/2 (revolutions)
        float gn = gv[j];
        float sp = (gn > 15.0f) ? gn : __logf(1.0f + __expf(gn));
        float gt = tv[j];
        float a  = (1.0f - gt) * sp * sp;
        // exact frac(l*f): split f at 12 mantissa bits
        float fh = __uint_as_float(__float_as_uint(f) & 0xFFFFF000u);
        float fl = f - fh;
        float t0 = lf * fh;
        float tr = t0 - floorf(t0);
        tr = __builtin_fmaf(lf, fl, tr);
        float pk = 6.28318530717958647f * tr;
        float pq = pk + ov[j];
        float sq = __sinf(pq), cq = __cosf(pq);
        float sk = __sinf(pk), ck = __cosf(pk);
        oq0[j] = (f16)(qv[j] * a * cq);
        oq1[j] = (f16)(qv[j] * a * sq);
        oq2[j] = (f16)(qv[j] * gt);
        ok0[j] = (f16)(kv[j] * ck);
        ok1[j] = (f16)(kv[j] * sk);
        ok2[j] = (f16)(kv[j]);
    }
    size_t base = ((size_t)nh * LQ + l) * ND + e0;
    *(f16x8*)(Qf + base)            = oq0;
    *(f16x8*)(Qf + base + NE)       = oq1;
    *(f16x8*)(Qf + base + 2 * NE)   = oq2;
    *(f16x8*)(Kf + base)            = ok0;
    *(f16x8*)(Kf + base + NE)       = ok1;
    *(f16x8*)(Kf + base + 2 * NE)   = ok2;
}

// ---------------- flash attention, f16 MFMA, async dbuf staging ----------------
// grid 256 (= CU count, 1 block/CU, balanced): nh = bid&31, lt = bid>>5
// (8 tiles of 96 q-rows). block 384 (6 waves, one 16-row A-tile each):
// 6 waves/CU, single staging stream per CU (no duplicate block staging).
// Softmax: max-tracked online, exp2 domain (VERIFIED r5 path — f16 P storage
// REQUIRES the max shift; no-max overflowed f16 -> NaN in r6).
// LDS: K chunks stored as 16B chunks, phys chunk p = r*24 + ((c&~7)|((c&7)^(r&7)))
//      V chunks: p = r*8 + (c ^ (r&7)). XOR swizzle -> uniform bank spread on
//      both the lane-linear async writes and the B-fragment b128 reads.
__global__ __launch_bounds__(384) void sinattn_flash(
    const f16* __restrict__ Qf, const f16* __restrict__ Kf, const f16* __restrict__ Vt,
    const float* __restrict__ mask, const float* __restrict__ keylen,
    float* __restrict__ out)
{
    __shared__ __attribute__((aligned(16))) f16 sK[2][64 * 24 * 8];  // 24 KB each
    __shared__ __attribute__((aligned(16))) f16 sV[2][64 * 8 * 8];   // 8 KB each
    __shared__ __attribute__((aligned(16))) f16 sP[6][16 * 72];      // per-wave

    int tid  = threadIdx.x;
    int wv   = tid / 64;                 // 0..5
    int lane = tid & 63;
    int grp  = lane >> 4;
    int r16  = lane & 15;
    int swz  = r16 & 7;

    int bid = blockIdx.x;
    int nh  = bid & 31;
    int lt  = bid >> 5;                  // 0..7
    int n   = nh >> 3;
    int l0  = lt * 96;
    int qrow0 = l0 + wv * 16;            // this wave's q-rows

    // per-lane swizzled global offsets for staging (384 threads/block)
    int goffK[4], goffV[2];
    #pragma unroll
    for (int i = 0; i < 4; ++i) {
        int p = i * 384 + tid;           // 0..1535
        int r = p / 24, c = p - r * 24;
        int cl = (c & ~7) | ((c & 7) ^ (r & 7));
        goffK[i] = r * ND + cl * 8;
    }
    #pragma unroll
    for (int i = 0; i < 2; ++i) {
        int p = i * 384 + tid;           // 0..767 (512 valid)
        int r = p >> 3, c = p & 7;
        goffV[i] = r * LQ + (c ^ (r & 7)) * 8;
    }
    const f16* Kb = Kf + (size_t)nh * LQ * ND;
    const f16* Vb = Vt + (size_t)nh * NE * LQ;

    // issue chunk 0 into buffer 0 (latency overlaps qf loads below)
    {
        #pragma unroll
        for (int i = 0; i < 4; ++i)
            stage16(&sK[0][(i * 384 + wv * 64) * 8], Kb + goffK[i], lane);
        stage16(&sV[0][(wv * 64) * 8], Vb + goffV[0], lane);
        if (tid < 128)   // waves 0,1 only: wave-uniform branch
            stage16(&sV[0][(384 + wv * 64) * 8], Vb + goffV[1], lane);
    }

    // Q fragments (A-layout) from global, live whole kernel: 24 VGPRs
    f16x8 qf[6];
    {
        size_t rbase = ((size_t)nh * LQ + qrow0 + r16) * ND + grp * 8;
        #pragma unroll
        for (int d0 = 0; d0 < 6; ++d0)
            qf[d0] = *(const f16x8*)(Qf + rbase + d0 * 32);
    }

    float m_i[4], l_i[4];
    f32x4 O[4];
    #pragma unroll
    for (int rr = 0; rr < 4; ++rr) { m_i[rr] = -INFINITY; l_i[rr] = 0.f; }
    #pragma unroll
    for (int tt = 0; tt < 4; ++tt)
        #pragma unroll
        for (int rr = 0; rr < 4; ++rr) O[tt][rr] = 0.f;

    for (int c = 0; c < 12; ++c) {
        int cur = c & 1;
        int s0  = c * 64;
        __syncthreads();   // drains vmcnt: sK/sV[cur] landed; prev compute done

        if (c < 11) {      // prefetch next chunk; in flight during this compute
            const f16* kg = Kb + (s0 + 64) * ND;
            const f16* vg = Vb + (s0 + 64);
            #pragma unroll
            for (int i = 0; i < 4; ++i)
                stage16(&sK[cur ^ 1][(i * 384 + wv * 64) * 8], kg + goffK[i], lane);
            stage16(&sV[cur ^ 1][(wv * 64) * 8], vg + goffV[0], lane);
            if (tid < 128)
                stage16(&sV[cur ^ 1][(384 + wv * 64) * 8], vg + goffV[1], lane);
        }

        // mask / keylen (zero-valued but semantically required; L2-resident)
        float klv[4], mreg[4][4];
        #pragma unroll
        for (int j = 0; j < 4; ++j) klv[j] = keylen[n * LQ + s0 + j * 16 + r16];
        #pragma unroll
        for (int rr = 0; rr < 4; ++rr) {
            int lrow = qrow0 + grp * 4 + rr;
            #pragma unroll
            for (int j = 0; j < 4; ++j)
                mreg[rr][j] = mask[lrow * LQ + s0 + j * 16 + r16];
        }

        // S = Q'.K'^T  (f16 MFMA)
        f32x4 st[4];
        #pragma unroll
        for (int j = 0; j < 4; ++j)
            #pragma unroll
            for (int rr = 0; rr < 4; ++rr) st[j][rr] = 0.f;
        #pragma unroll
        for (int d0 = 0; d0 < 6; ++d0) {
            #pragma unroll
            for (int j = 0; j < 4; ++j) {
                int cc = d0 * 4 + grp;
                int cl = (cc & ~7) | ((cc & 7) ^ swz);
                f16x8 bf = *(const f16x8*)&sK[cur][((j * 16 + r16) * 24 + cl) * 8];
                st[j] = __builtin_amdgcn_mfma_f32_16x16x32_f16(qf[d0], bf, st[j], 0, 0, 0);
            }
        }

        // online softmax in exp2 domain (C layout: col=r16+16j, row=grp*4+rr)
        #pragma unroll
        for (int rr = 0; rr < 4; ++rr) {
            float lg[4];
            float mx = -INFINITY;
            #pragma unroll
            for (int j = 0; j < 4; ++j) {
                lg[j] = TEMP2 * (st[j][rr] + mreg[rr][j] + klv[j]);
                mx = fmaxf(mx, lg[j]);
            }
            mx = red16_max(mx);
            float mnew  = fmaxf(m_i[rr], mx);
            float alpha = fexp2(m_i[rr] - mnew);
            float rs = 0.f;
            #pragma unroll
            for (int j = 0; j < 4; ++j) {
                float p = fexp2(lg[j] - mnew);
                rs += p;
                sP[wv][(grp * 4 + rr) * 72 + j * 16 + r16] = (f16)p;
            }
            rs = red16_sum(rs);
            l_i[rr] = l_i[rr] * alpha + rs;
            m_i[rr] = mnew;
            #pragma unroll
            for (int tt = 0; tt < 4; ++tt) O[tt][rr] *= alpha;
        }
        // no barrier: sP round-trip is per-wave; LDS ops in-order per wave

        // O += P.V
        #pragma unroll
        for (int kk = 0; kk < 2; ++kk) {
            f16x8 pa = *(const f16x8*)&sP[wv][r16 * 72 + kk * 32 + grp * 8];
            #pragma unroll
            for (int tt = 0; tt < 4; ++tt) {
                int cc = kk * 4 + grp;
                f16x8 vb = *(const f16x8*)&sV[cur][((tt * 16 + r16) * 8 + (cc ^ swz)) * 8];
                O[tt] = __builtin_amdgcn_mfma_f32_16x16x32_f16(pa, vb, O[tt], 0, 0, 0);
            }
        }
    }

    // epilogue: normalize, write out[n][l][h][e] (fp32)
    #pragma unroll
    for (int rr = 0; rr < 4; ++rr) {
        float inv = 1.0f / l_i[rr];
        int lrow = qrow0 + grp * 4 + rr;
        float* op = out + ((size_t)(n * LQ + lrow) * NH + (nh & 7)) * NE;
        #pragma unroll
        for (int tt = 0; tt < 4; ++tt)
            op[tt * 16 + r16] = O[tt][rr] * inv;
    }
}

extern "C" void kernel_launch(void* const* d_in, const int* in_sizes, int n_in,
                              void* d_out, int out_size, void* d_ws, size_t ws_size,
                              hipStream_t stream)
{
    const float* Q      = (const float*)d_in[0];
    const float* K      = (const float*)d_in[1];
    const float* V      = (const float*)d_in[2];
    const float* mask   = (const float*)d_in[3];
    const float* keylen = (const float*)d_in[4];
    const float* freqs  = (const float*)d_in[5];
    const float* offs   = (const float*)d_in[6];
    const float* gains  = (const float*)d_in[7];
    const float* gate   = (const float*)d_in[8];
    float* out = (float*)d_out;

    const size_t P = (size_t)NB * NH * LQ * ND;   // 4.72M elems / plane
    f16* Qf = (f16*)d_ws;
    f16* Kf = Qf + P;
    f16* Vt = Kf + P;                             // 32*64*768 f16 = 3.1 MB

    sinattn_prep<<<768 + 384, 256, 0, stream>>>(Q, K, V, freqs, offs, gains, gate,
                                                Qf, Kf, Vt);
    sinattn_flash<<<NB * NH * (LQ / 96), 384, 0, stream>>>(Qf, Kf, Vt,
                                                           mask, keylen, out);
}

// Round 8
// 113.154 us; speedup vs baseline: 1.2500x; 1.0094x over previous
//
#include <hip/hip_runtime.h>
#include <math.h>
#include <stdint.h>

#define NB 4
#define LQ 768
#define NH 8
#define NE 64
#define ND 192   // 3*E augmented feature dim
// TEMP * log2(e): softmax computed in exp2 domain (1 transcendental per p)
#define TEMP2 0.18033688011112042f

typedef _Float16 f16;
typedef __attribute__((ext_vector_type(8))) _Float16 f16x8;
typedef __attribute__((ext_vector_type(4))) float f32x4;

// Async global->LDS 16B: HW writes lds_base + lane*16. lds_base must be
// wave-uniform; global address is per-lane.
__device__ __forceinline__ void stage16(f16* lds_base, const f16* g, int lane) {
#if __has_builtin(__builtin_amdgcn_global_load_lds)
    __builtin_amdgcn_global_load_lds(
        (const __attribute__((address_space(1))) uint32_t*)g,
        (__attribute__((address_space(3))) uint32_t*)lds_base, 16, 0, 0);
#else
    *(uint4*)((char*)lds_base + lane * 16) = *(const uint4*)g;
#endif
}

__device__ __forceinline__ float fexp2(float x) {
#if __has_builtin(__builtin_amdgcn_exp2f)
    return __builtin_amdgcn_exp2f(x);
#else
    return exp2f(x);
#endif
}

// Pure-VALU 16-lane reductions via DPP (no DS-pipe traffic). Verified r2/r5/r7.
template <int CTRL>
__device__ __forceinline__ float dppf(float x) {
    union { float f; int i; } u, r;
    u.f = x;
    r.i = __builtin_amdgcn_update_dpp(u.i, u.i, CTRL, 0xF, 0xF, false);
    return r.f;
}
__device__ __forceinline__ float red16_max(float x) {
    x = fmaxf(x, dppf<0xB1>(x));
    x = fmaxf(x, dppf<0x4E>(x));
    x = fmaxf(x, dppf<0x141>(x));
    x = fmaxf(x, dppf<0x140>(x));
    return x;
}
__device__ __forceinline__ float red16_sum(float x) {
    x += dppf<0xB1>(x);
    x += dppf<0x4E>(x);
    x += dppf<0x141>(x);
    x += dppf<0x140>(x);
    return x;
}

// ------- merged prep (blocks 0..767) + V transpose (blocks 768..1151) -------
// Verified round-7. prep: augmented f16 Q'/K'. vt: V -> Vt[nh][e][s] f16.
__global__ __launch_bounds__(256) void sinattn_prep(
    const float* __restrict__ Q, const float* __restrict__ K,
    const float* __restrict__ V,
    const float* __restrict__ freqs, const float* __restrict__ offsets,
    const float* __restrict__ gains, const float* __restrict__ gate,
    f16* __restrict__ Qf, f16* __restrict__ Kf, f16* __restrict__ Vt)
{
    __shared__ f16 tile[64][72];
    int bid = blockIdx.x;
    int tid = threadIdx.x;

    if (bid >= 768) {
        // ---- V transpose ----
        int b = bid - 768;
        int st = b % 12, nh = b / 12;
        int n = nh >> 3, h = nh & 7;
        int s0 = st * 64;

        int sl = tid >> 2, e0 = (tid & 3) << 4;
        const float4* vp = (const float4*)(V + ((size_t)(n * LQ + s0 + sl) * NH + h) * NE + e0);
        float4 a0 = vp[0], a1 = vp[1], a2 = vp[2], a3 = vp[3];
        float vv[16] = { a0.x,a0.y,a0.z,a0.w, a1.x,a1.y,a1.z,a1.w,
                         a2.x,a2.y,a2.z,a2.w, a3.x,a3.y,a3.z,a3.w };
        #pragma unroll
        for (int j = 0; j < 16; ++j) tile[e0 + j][sl] = (f16)vv[j];
        __syncthreads();

        int er = tid >> 2, sc = tid & 3;
        f16* op = Vt + ((size_t)nh * NE + er) * LQ + s0 + sc * 16;
        *(uint4*)op       = *(const uint4*)&tile[er][sc * 16];
        *(uint4*)(op + 8) = *(const uint4*)&tile[er][sc * 16 + 8];
        return;
    }

    // ---- prep ----
    int idx = bid * 256 + tid;                  // ((n*L+l)*8 + h)*8 + eg
    int eg = idx & 7, e0 = eg << 3;
    int h  = (idx >> 3) & 7;
    int t  = idx >> 6;                          // n*L + l
    int l  = t % LQ;
    int n  = t / LQ;
    int nh = (n << 3) | h;
    int he = (h << 6) | e0;

    const float* qp = Q + (size_t)idx * 8;      // == ((t*8+h)*64 + e0)
    const float* kp = K + (size_t)idx * 8;
    float4 q0 = *(const float4*)qp, q1 = *(const float4*)(qp + 4);
    float4 k0 = *(const float4*)kp, k1 = *(const float4*)(kp + 4);
    float qv[8] = {q0.x,q0.y,q0.z,q0.w, q1.x,q1.y,q1.z,q1.w};
    float kv[8] = {k0.x,k0.y,k0.z,k0.w, k1.x,k1.y,k1.z,k1.w};

    float4 fA = *(const float4*)(freqs   + he), fB = *(const float4*)(freqs   + he + 4);
    float4 oA = *(const float4*)(offsets + he), oB = *(const float4*)(offsets + he + 4);
    float4 gA = *(const float4*)(gains   + he), gB = *(const float4*)(gains   + he + 4);
    float4 tA = *(const float4*)(gate    + he), tB = *(const float4*)(gate    + he + 4);
    float fv[8] = {fA.x,fA.y,fA.z,fA.w, fB.x,fB.y,fB.z,fB.w};
    float ov[8] = {oA.x,oA.y,oA.z,oA.w, oB.x,oB.y,oB.z,oB.w};
    float gv[8] = {gA.x,gA.y,gA.z,gA.w, gB.x,gB.y,gB.z,gB.w};
    float tv[8] = {tA.x,tA.y,tA.z,tA.w, tB.x,tB.y,tB.z,tB.w};

    f16x8 oq0, oq1, oq2, ok0, ok1, ok2;
    float lf = (float)l;
    #pragma unroll
    for (int j = 0; j < 8; ++j) {
        float f  = 0.5f / (1.0f + __expf(-fv[j]));        // sigmoid/2 (revolutions)
        float gn = gv[j];
        float sp = (gn > 15.0f) ? gn : __logf(1.0f + __expf(gn));
        float gt = tv[j];
        float a  = (1.0f - gt) * sp * sp;
        // exact frac(l*f): split f at 12 mantissa bits
        float fh = __uint_as_float(__float_as_uint(f) & 0xFFFFF000u);
        float fl = f - fh;
        float t0 = lf * fh;
        float tr = t0 - floorf(t0);
        tr = __builtin_fmaf(lf, fl, tr);
        float pk = 6.28318530717958647f * tr;
        float pq = pk + ov[j];
        float sq = __sinf(pq), cq = __cosf(pq);
        float sk = __sinf(pk), ck = __cosf(pk);
        oq0[j] = (f16)(qv[j] * a * cq);
        oq1[j] = (f16)(qv[j] * a * sq);
        oq2[j] = (f16)(qv[j] * gt);
        ok0[j] = (f16)(kv[j] * ck);
        ok1[j] = (f16)(kv[j] * sk);
        ok2[j] = (f16)(kv[j]);
    }
    size_t base = ((size_t)nh * LQ + l) * ND + e0;
    *(f16x8*)(Qf + base)            = oq0;
    *(f16x8*)(Qf + base + NE)       = oq1;
    *(f16x8*)(Qf + base + 2 * NE)   = oq2;
    *(f16x8*)(Kf + base)            = ok0;
    *(f16x8*)(Kf + base + NE)       = ok1;
    *(f16x8*)(Kf + base + 2 * NE)   = ok2;
}

// ---------------- flash attention, f16 MFMA, async dbuf staging ----------------
// grid 256 (1 block/CU): nh = bid&31, lt = bid>>5 (8 tiles of 96 q-rows).
// block 384 (6 waves, one 16-row A-tile each). KVBLK=128: 6 chunk iterations
// (half the barriers/drains of r7), same verified per-wave layouts.
// Softmax: max-tracked online, exp2 domain (f16 P REQUIRES the max shift).
// LDS (153.6 KB): sK 2x48KB, sV 2x16KB, sP 6x(16x136) f16.
//   K chunks (16B): phys p = r*24 + ((c&~7)|((c&7)^(r&7))), r=0..127
//   V chunks (16B): phys p = r*16 + ((c&~7)|((c&7)^(r&7))), r=e=0..63, c=0..15
__global__ __launch_bounds__(384) void sinattn_flash(
    const f16* __restrict__ Qf, const f16* __restrict__ Kf, const f16* __restrict__ Vt,
    const float* __restrict__ mask, const float* __restrict__ keylen,
    float* __restrict__ out)
{
    __shared__ __attribute__((aligned(16))) f16 sK[2][128 * 24 * 8]; // 48 KB each
    __shared__ __attribute__((aligned(16))) f16 sV[2][64 * 16 * 8];  // 16 KB each
    __shared__ __attribute__((aligned(16))) f16 sP[6][16 * 136];     // per-wave

    int tid  = threadIdx.x;
    int wv   = tid / 64;                 // 0..5
    int lane = tid & 63;
    int grp  = lane >> 4;
    int r16  = lane & 15;
    int swz  = r16 & 7;

    int bid = blockIdx.x;
    int nh  = bid & 31;
    int lt  = bid >> 5;                  // 0..7
    int n   = nh >> 3;
    int l0  = lt * 96;
    int qrow0 = l0 + wv * 16;            // this wave's q-rows

    // per-lane swizzled global offsets for staging (384 threads/block)
    int goffK[8], goffV[3];
    #pragma unroll
    for (int i = 0; i < 8; ++i) {
        int p = i * 384 + tid;           // 0..3071
        int r = p / 24, c = p - r * 24;
        int cl = (c & ~7) | ((c & 7) ^ (r & 7));
        goffK[i] = r * ND + cl * 8;
    }
    #pragma unroll
    for (int i = 0; i < 3; ++i) {
        int p = i * 384 + tid;           // 0..1151 (1024 valid)
        int r = p >> 4, c = p & 15;
        int cl = (c & ~7) | ((c & 7) ^ (r & 7));
        goffV[i] = r * LQ + cl * 8;
    }
    const f16* Kb = Kf + (size_t)nh * LQ * ND;
    const f16* Vb = Vt + (size_t)nh * NE * LQ;

    // issue chunk 0 into buffer 0 (latency overlaps qf loads below)
    {
        #pragma unroll
        for (int i = 0; i < 8; ++i)
            stage16(&sK[0][(i * 384 + wv * 64) * 8], Kb + goffK[i], lane);
        #pragma unroll
        for (int i = 0; i < 2; ++i)
            stage16(&sV[0][(i * 384 + wv * 64) * 8], Vb + goffV[i], lane);
        if (tid < 256)   // waves 0..3: wave-uniform branch (chunks 768..1023)
            stage16(&sV[0][(768 + wv * 64) * 8], Vb + goffV[2], lane);
    }

    // Q fragments (A-layout) from global, live whole kernel: 24 VGPRs
    f16x8 qf[6];
    {
        size_t rbase = ((size_t)nh * LQ + qrow0 + r16) * ND + grp * 8;
        #pragma unroll
        for (int d0 = 0; d0 < 6; ++d0)
            qf[d0] = *(const f16x8*)(Qf + rbase + d0 * 32);
    }

    float m_i[4], l_i[4];
    f32x4 O[4];
    #pragma unroll
    for (int rr = 0; rr < 4; ++rr) { m_i[rr] = -INFINITY; l_i[rr] = 0.f; }
    #pragma unroll
    for (int tt = 0; tt < 4; ++tt)
        #pragma unroll
        for (int rr = 0; rr < 4; ++rr) O[tt][rr] = 0.f;

    for (int c = 0; c < 6; ++c) {
        int cur = c & 1;
        int s0  = c * 128;
        __syncthreads();   // drains vmcnt: sK/sV[cur] landed; prev compute done

        if (c < 5) {       // prefetch next chunk; in flight during this compute
            const f16* kg = Kb + (s0 + 128) * ND;
            const f16* vg = Vb + (s0 + 128);
            #pragma unroll
            for (int i = 0; i < 8; ++i)
                stage16(&sK[cur ^ 1][(i * 384 + wv * 64) * 8], kg + goffK[i], lane);
            #pragma unroll
            for (int i = 0; i < 2; ++i)
                stage16(&sV[cur ^ 1][(i * 384 + wv * 64) * 8], vg + goffV[i], lane);
            if (tid < 256)
                stage16(&sV[cur ^ 1][(768 + wv * 64) * 8], vg + goffV[2], lane);
        }

        // mask / keylen (zero-valued but semantically required; L2-resident)
        float klv[8], mreg[4][8];
        #pragma unroll
        for (int j = 0; j < 8; ++j) klv[j] = keylen[n * LQ + s0 + j * 16 + r16];
        #pragma unroll
        for (int rr = 0; rr < 4; ++rr) {
            int lrow = qrow0 + grp * 4 + rr;
            #pragma unroll
            for (int j = 0; j < 8; ++j)
                mreg[rr][j] = mask[lrow * LQ + s0 + j * 16 + r16];
        }

        // S = Q'.K'^T  (f16 MFMA)
        f32x4 st[8];
        #pragma unroll
        for (int j = 0; j < 8; ++j)
            #pragma unroll
            for (int rr = 0; rr < 4; ++rr) st[j][rr] = 0.f;
        __builtin_amdgcn_s_setprio(1);
        #pragma unroll
        for (int d0 = 0; d0 < 6; ++d0) {
            #pragma unroll
            for (int j = 0; j < 8; ++j) {
                int cc = d0 * 4 + grp;
                int cl = (cc & ~7) | ((cc & 7) ^ swz);
                f16x8 bf = *(const f16x8*)&sK[cur][((j * 16 + r16) * 24 + cl) * 8];
                st[j] = __builtin_amdgcn_mfma_f32_16x16x32_f16(qf[d0], bf, st[j], 0, 0, 0);
            }
        }
        __builtin_amdgcn_s_setprio(0);

        // online softmax in exp2 domain (C layout: col=r16+16j, row=grp*4+rr)
        #pragma unroll
        for (int rr = 0; rr < 4; ++rr) {
            float lg[8];
            float mx = -INFINITY;
            #pragma unroll
            for (int j = 0; j < 8; ++j) {
                lg[j] = TEMP2 * (st[j][rr] + mreg[rr][j] + klv[j]);
                mx = fmaxf(mx, lg[j]);
            }
            mx = red16_max(mx);
            float mnew  = fmaxf(m_i[rr], mx);
            float alpha = fexp2(m_i[rr] - mnew);
            float rs = 0.f;
            #pragma unroll
            for (int j = 0; j < 8; ++j) {
                float p = fexp2(lg[j] - mnew);
                rs += p;
                sP[wv][(grp * 4 + rr) * 136 + j * 16 + r16] = (f16)p;
            }
            rs = red16_sum(rs);
            l_i[rr] = l_i[rr] * alpha + rs;
            m_i[rr] = mnew;
            #pragma unroll
            for (int tt = 0; tt < 4; ++tt) O[tt][rr] *= alpha;
        }
        // no barrier: sP round-trip is per-wave; LDS ops in-order per wave

        // O += P.V
        __builtin_amdgcn_s_setprio(1);
        #pragma unroll
        for (int kk = 0; kk < 4; ++kk) {
            f16x8 pa = *(const f16x8*)&sP[wv][r16 * 136 + kk * 32 + grp * 8];
            #pragma unroll
            for (int tt = 0; tt < 4; ++tt) {
                int cc = kk * 4 + grp;
                int cl = (cc & ~7) | ((cc & 7) ^ swz);
                f16x8 vb = *(const f16x8*)&sV[cur][((tt * 16 + r16) * 16 + cl) * 8];
                O[tt] = __builtin_amdgcn_mfma_f32_16x16x32_f16(pa, vb, O[tt], 0, 0, 0);
            }
        }
        __builtin_amdgcn_s_setprio(0);
    }

    // epilogue: normalize, write out[n][l][h][e] (fp32)
    #pragma unroll
    for (int rr = 0; rr < 4; ++rr) {
        float inv = 1.0f / l_i[rr];
        int lrow = qrow0 + grp * 4 + rr;
        float* op = out + ((size_t)(n * LQ + lrow) * NH + (nh & 7)) * NE;
        #pragma unroll
        for (int tt = 0; tt < 4; ++tt)
            op[tt * 16 + r16] = O[tt][rr] * inv;
    }
}

extern "C" void kernel_launch(void* const* d_in, const int* in_sizes, int n_in,
                              void* d_out, int out_size, void* d_ws, size_t ws_size,
                              hipStream_t stream)
{
    const float* Q      = (const float*)d_in[0];
    const float* K      = (const float*)d_in[1];
    const float* V      = (const float*)d_in[2];
    const float* mask   = (const float*)d_in[3];
    const float* keylen = (const float*)d_in[4];
    const float* freqs  = (const float*)d_in[5];
    const float* offs   = (const float*)d_in[6];
    const float* gains  = (const float*)d_in[7];
    const float* gate   = (const float*)d_in[8];
    float* out = (float*)d_out;

    const size_t P = (size_t)NB * NH * LQ * ND;   // 4.72M elems / plane
    f16* Qf = (f16*)d_ws;
    f16* Kf = Qf + P;
    f16* Vt = Kf + P;                             // 32*64*768 f16 = 3.1 MB

    sinattn_prep<<<768 + 384, 256, 0, stream>>>(Q, K, V, freqs, offs, gains, gate,
                                                Qf, Kf, Vt);
    sinattn_flash<<<NB * NH * (LQ / 96), 384, 0, stream>>>(Qf, Kf, Vt,
                                                           mask, keylen, out);
}